// Round 1
// baseline (943.649 us; speedup 1.0000x reference)
//
#include <hip/hip_runtime.h>
#include <math.h>

#ifndef M_PI
#define M_PI 3.14159265358979323846
#endif

#define QPTS 1048576
#define MG 32
#define NG 32
#define LB 8
#define DD 12
#define HH 48
#define HGATE 24
#define PEF 4
#define PEDIM 27

// ---------------------------------------------------------------------------
// Pre-kernel: per-Gaussian precision matrices (64 Gaussians total).
// ws layout: [64][9] = {P00,P11,P22,2*P01,2*P02,2*P12,mux,muy,muz}
//  [0..31] coeff Gaussians, [32..63] basis Gaussians.
// ---------------------------------------------------------------------------
__global__ __launch_bounds__(64) void precompute_gauss_kernel(
    const float* __restrict__ coeff_mu, const float* __restrict__ coeff_log_s,
    const float* __restrict__ coeff_q,
    const float* __restrict__ basis_mu, const float* __restrict__ basis_log_s,
    const float* __restrict__ basis_q,
    float* __restrict__ ws)
{
    int t = threadIdx.x;
    if (t >= 64) return;
    const float *mu, *ls, *qq;
    float* o;
    int k;
    if (t < MG) { mu = coeff_mu; ls = coeff_log_s; qq = coeff_q; o = ws;        k = t; }
    else        { mu = basis_mu; ls = basis_log_s; qq = basis_q; o = ws + MG*9; k = t - MG; }

    float qw = qq[k*4+0], qx = qq[k*4+1], qy = qq[k*4+2], qz = qq[k*4+3];
    float n = sqrtf(qw*qw + qx*qx + qy*qy + qz*qz) + 1e-8f;
    qw /= n; qx /= n; qy /= n; qz /= n;

    float R00 = 1.f - 2.f*(qy*qy + qz*qz), R01 = 2.f*(qx*qy - qw*qz), R02 = 2.f*(qx*qz + qw*qy);
    float R10 = 2.f*(qx*qy + qw*qz), R11 = 1.f - 2.f*(qx*qx + qz*qz), R12 = 2.f*(qy*qz - qw*qx);
    float R20 = 2.f*(qx*qz - qw*qy), R21 = 2.f*(qy*qz + qw*qx), R22 = 1.f - 2.f*(qx*qx + qy*qy);

    float s0 = expf(ls[k*3+0]), s1 = expf(ls[k*3+1]), s2 = expf(ls[k*3+2]);
    float i0 = 1.f/(s0*s0 + 1e-8f), i1 = 1.f/(s1*s1 + 1e-8f), i2 = 1.f/(s2*s2 + 1e-8f);

    float P00 = R00*R00*i0 + R01*R01*i1 + R02*R02*i2;
    float P11 = R10*R10*i0 + R11*R11*i1 + R12*R12*i2;
    float P22 = R20*R20*i0 + R21*R21*i1 + R22*R22*i2;
    float P01 = R00*R10*i0 + R01*R11*i1 + R02*R12*i2;
    float P02 = R00*R20*i0 + R01*R21*i1 + R02*R22*i2;
    float P12 = R10*R20*i0 + R11*R21*i1 + R12*R22*i2;

    o[k*9+0] = P00; o[k*9+1] = P11; o[k*9+2] = P22;
    o[k*9+3] = 2.f*P01; o[k*9+4] = 2.f*P02; o[k*9+5] = 2.f*P12;
    o[k*9+6] = mu[k*3+0]; o[k*9+7] = mu[k*3+1]; o[k*9+8] = mu[k*3+2];
}

// Normalized anisotropic-Gaussian weights for K Gaussians, fully unrolled.
template<int K>
__device__ __forceinline__ void gauss_norm_weights(const float* __restrict__ g9,
                                                   float px, float py, float pz,
                                                   float* w)
{
#pragma unroll
    for (int k = 0; k < K; ++k) {
        float a = g9[k*9+0], b = g9[k*9+1], c = g9[k*9+2];
        float d = g9[k*9+3], e = g9[k*9+4], f = g9[k*9+5];
        float dx = px - g9[k*9+6], dy = py - g9[k*9+7], dz = pz - g9[k*9+8];
        float maha = a*dx*dx;
        maha = fmaf(b, dy*dy, maha);
        maha = fmaf(c, dz*dz, maha);
        maha = fmaf(d, dx*dy, maha);
        maha = fmaf(e, dx*dz, maha);
        maha = fmaf(f, dy*dz, maha);
        w[k] = __expf(-0.5f * maha);
    }
    float sum = 0.f;
#pragma unroll
    for (int k = 0; k < K; ++k) sum += w[k];
    float inv = 1.f / (sum + 1e-8f);
#pragma unroll
    for (int k = 0; k < K; ++k) w[k] *= inv;
}

// ---------------------------------------------------------------------------
// Main kernel: one thread per query point.
// ---------------------------------------------------------------------------
__global__ __launch_bounds__(256, 2) void mbd_main_kernel(
    const float* __restrict__ coords,
    const float* __restrict__ gpre,      // ws from precompute
    const float* __restrict__ C,         // [32,8]
    const float* __restrict__ B,         // [32,8,12]
    const float* __restrict__ fw0, const float* __restrict__ fb0,
    const float* __restrict__ fw1, const float* __restrict__ fb1,
    const float* __restrict__ fw2, const float* __restrict__ fb2,
    const float* __restrict__ gw0, const float* __restrict__ gb0,
    const float* __restrict__ gw1, const float* __restrict__ gb1,
    const float* __restrict__ rw0, const float* __restrict__ rb0,
    const float* __restrict__ rw1, const float* __restrict__ rb1,
    float* __restrict__ out)
{
    int q = blockIdx.x * 256 + threadIdx.x;
    if (q >= QPTS) return;

    float px = coords[q*3+0], py = coords[q*3+1], pz = coords[q*3+2];

    // ---------------- phi -> moving_coeff ----------------
    float mc[LB];
    {
        float phi[MG];
        gauss_norm_weights<MG>(gpre, px, py, pz, phi);
#pragma unroll
        for (int l = 0; l < LB; ++l) mc[l] = 0.f;
#pragma unroll
        for (int k = 0; k < MG; ++k) {
            float p = phi[k];
#pragma unroll
            for (int l = 0; l < LB; ++l) mc[l] = fmaf(p, C[k*LB+l], mc[l]);
        }
    }
    {   // store moving_coeff at out + Q*12 + q*8
        float4* o = (float4*)(out + (size_t)QPTS*DD + (size_t)q*LB);
        o[0] = make_float4(mc[0], mc[1], mc[2], mc[3]);
        o[1] = make_float4(mc[4], mc[5], mc[6], mc[7]);
    }

    // ---------------- psi ----------------
    float psi[NG];
    gauss_norm_weights<NG>(gpre + MG*9, px, py, pz, psi);

    // ---------------- moving_basis + coarse ----------------
    float coarse[DD];
#pragma unroll
    for (int d = 0; d < DD; ++d) coarse[d] = 0.f;

    float* omb = out + (size_t)QPTS*(DD+LB) + (size_t)q*(LB*DD);
#pragma unroll
    for (int l = 0; l < LB; ++l) {
        float mb[DD];
#pragma unroll
        for (int d = 0; d < DD; ++d) mb[d] = 0.f;
#pragma unroll
        for (int n = 0; n < NG; ++n) {
            float p = psi[n];
            const float* brow = B + (n*LB + l)*DD;
#pragma unroll
            for (int d = 0; d < DD; ++d) mb[d] = fmaf(p, brow[d], mb[d]);
        }
        float4* o = (float4*)(omb + l*DD);
        o[0] = make_float4(mb[0], mb[1], mb[2], mb[3]);
        o[1] = make_float4(mb[4], mb[5], mb[6], mb[7]);
        o[2] = make_float4(mb[8], mb[9], mb[10], mb[11]);
        float ml = mc[l];
#pragma unroll
        for (int d = 0; d < DD; ++d) coarse[d] = fmaf(ml, mb[d], coarse[d]);
    }
    {   // store coarse at out + Q*116 + q*12
        float4* o = (float4*)(out + (size_t)QPTS*(DD+LB+LB*DD) + (size_t)q*DD);
        o[0] = make_float4(coarse[0], coarse[1], coarse[2], coarse[3]);
        o[1] = make_float4(coarse[4], coarse[5], coarse[6], coarse[7]);
        o[2] = make_float4(coarse[8], coarse[9], coarse[10], coarse[11]);
    }

    // ---------------- fine branch: PE + MLP ----------------
    float pe[PEDIM];
    pe[0] = px; pe[1] = py; pe[2] = pz;
#pragma unroll
    for (int i = 0; i < PEF; ++i) {
        float fpi = (float)(M_PI * (double)(1 << i));
        pe[3+6*i+0] = __sinf(fpi*px);
        pe[3+6*i+1] = __sinf(fpi*py);
        pe[3+6*i+2] = __sinf(fpi*pz);
        pe[3+6*i+3] = __cosf(fpi*px);
        pe[3+6*i+4] = __cosf(fpi*py);
        pe[3+6*i+5] = __cosf(fpi*pz);
    }

    float h0[HH];
#pragma unroll
    for (int j = 0; j < HH; ++j) h0[j] = fb0[j];
#pragma unroll
    for (int k = 0; k < PEDIM; ++k) {
        float x = pe[k];
#pragma unroll
        for (int j = 0; j < HH; ++j) h0[j] = fmaf(x, fw0[k*HH+j], h0[j]);
    }
#pragma unroll
    for (int j = 0; j < HH; ++j) h0[j] = fmaxf(h0[j], 0.f);

    float h1[HH];
#pragma unroll
    for (int j = 0; j < HH; ++j) h1[j] = fb1[j];
#pragma unroll
    for (int k = 0; k < HH; ++k) {
        float x = h0[k];
#pragma unroll
        for (int j = 0; j < HH; ++j) h1[j] = fmaf(x, fw1[k*HH+j], h1[j]);
    }
#pragma unroll
    for (int j = 0; j < HH; ++j) h1[j] = fmaxf(h1[j], 0.f);

    float fine[DD];
#pragma unroll
    for (int d = 0; d < DD; ++d) fine[d] = fb2[d];
#pragma unroll
    for (int k = 0; k < HH; ++k) {
        float x = h1[k];
#pragma unroll
        for (int d = 0; d < DD; ++d) fine[d] = fmaf(x, fw2[k*DD+d], fine[d]);
    }

    // ---------------- gate ----------------
    float gacc = gb1[0];
#pragma unroll
    for (int j = 0; j < HGATE; ++j) {
        float hj = fmaf(px, gw0[0*HGATE+j], gb0[j]);
        hj = fmaf(py, gw0[1*HGATE+j], hj);
        hj = fmaf(pz, gw0[2*HGATE+j], hj);
        hj = fmaxf(hj, 0.f);
        gacc = fmaf(hj, gw1[j], gacc);
    }
    float gate = 1.f / (1.f + __expf(-gacc));

    // ---------------- blend + residual refiner ----------------
    float blended[DD];
#pragma unroll
    for (int d = 0; d < DD; ++d)
        blended[d] = (1.f - gate)*coarse[d] + gate*fine[d];

    float rh[HGATE];
#pragma unroll
    for (int j = 0; j < HGATE; ++j) rh[j] = rb0[j];
#pragma unroll
    for (int k = 0; k < DD; ++k) {
        float x = blended[k];
#pragma unroll
        for (int j = 0; j < HGATE; ++j) rh[j] = fmaf(x, rw0[k*HGATE+j], rh[j]);
    }
#pragma unroll
    for (int j = 0; j < HGATE; ++j) rh[j] = fmaf(px, rw0[12*HGATE+j], rh[j]);
#pragma unroll
    for (int j = 0; j < HGATE; ++j) rh[j] = fmaf(py, rw0[13*HGATE+j], rh[j]);
#pragma unroll
    for (int j = 0; j < HGATE; ++j) rh[j] = fmaf(pz, rw0[14*HGATE+j], rh[j]);
#pragma unroll
    for (int j = 0; j < HGATE; ++j) rh[j] = fmaxf(rh[j], 0.f);

    float rec[DD];
#pragma unroll
    for (int d = 0; d < DD; ++d) rec[d] = rb1[d];
#pragma unroll
    for (int k = 0; k < HGATE; ++k) {
        float x = rh[k];
#pragma unroll
        for (int d = 0; d < DD; ++d) rec[d] = fmaf(x, rw1[k*DD+d], rec[d]);
    }
#pragma unroll
    for (int d = 0; d < DD; ++d) rec[d] = fmaf(0.1f, rec[d], blended[d]);

    {   // store reconstruction at out + q*12
        float4* o = (float4*)(out + (size_t)q*DD);
        o[0] = make_float4(rec[0], rec[1], rec[2], rec[3]);
        o[1] = make_float4(rec[4], rec[5], rec[6], rec[7]);
        o[2] = make_float4(rec[8], rec[9], rec[10], rec[11]);
    }
}

extern "C" void kernel_launch(void* const* d_in, const int* in_sizes, int n_in,
                              void* d_out, int out_size, void* d_ws, size_t ws_size,
                              hipStream_t stream)
{
    const float* coords      = (const float*)d_in[0];
    const float* coeff_mu    = (const float*)d_in[1];
    const float* coeff_log_s = (const float*)d_in[2];
    const float* coeff_q     = (const float*)d_in[3];
    const float* basis_mu    = (const float*)d_in[4];
    const float* basis_log_s = (const float*)d_in[5];
    const float* basis_q     = (const float*)d_in[6];
    const float* C   = (const float*)d_in[7];
    const float* B   = (const float*)d_in[8];
    const float* fw0 = (const float*)d_in[9];  const float* fb0 = (const float*)d_in[10];
    const float* fw1 = (const float*)d_in[11]; const float* fb1 = (const float*)d_in[12];
    const float* fw2 = (const float*)d_in[13]; const float* fb2 = (const float*)d_in[14];
    const float* gw0 = (const float*)d_in[15]; const float* gb0 = (const float*)d_in[16];
    const float* gw1 = (const float*)d_in[17]; const float* gb1 = (const float*)d_in[18];
    const float* rw0 = (const float*)d_in[19]; const float* rb0 = (const float*)d_in[20];
    const float* rw1 = (const float*)d_in[21]; const float* rb1 = (const float*)d_in[22];

    float* out  = (float*)d_out;
    float* gpre = (float*)d_ws;   // 64*9 floats

    hipLaunchKernelGGL(precompute_gauss_kernel, dim3(1), dim3(64), 0, stream,
                       coeff_mu, coeff_log_s, coeff_q,
                       basis_mu, basis_log_s, basis_q, gpre);

    hipLaunchKernelGGL(mbd_main_kernel, dim3(QPTS/256), dim3(256), 0, stream,
                       coords, gpre, C, B,
                       fw0, fb0, fw1, fb1, fw2, fb2,
                       gw0, gb0, gw1, gb1,
                       rw0, rb0, rw1, rb1, out);
}